// Round 10
// baseline (198.360 us; speedup 1.0000x reference)
//
#include <hip/hip_runtime.h>

#define EPSV  1e-4f
#define LOG2E 1.44269504088896341f
#define LN2   0.69314718055994531f
#define TSC   (2.0f * LOG2E)

typedef float v2f __attribute__((ext_vector_type(2)));

constexpr int CH = 16;

// DPP quad-permute helpers (VALU pipe, register-only)
__device__ __forceinline__ float dpp_xor1(float v) {
    int i = __builtin_bit_cast(int, v);
    i = __builtin_amdgcn_update_dpp(i, i, 0xB1, 0xF, 0xF, false); // quad_perm [1,0,3,2]
    return __builtin_bit_cast(float, i);
}
__device__ __forceinline__ float dpp_xor2(float v) {
    int i = __builtin_bit_cast(int, v);
    i = __builtin_amdgcn_update_dpp(i, i, 0x4E, 0xF, 0xF, false); // quad_perm [2,3,0,1]
    return __builtin_bit_cast(float, i);
}
template<int IMM>
__device__ __forceinline__ float qbcast(float v) {              // broadcast lane Q of quad (IMM = Q*0x55)
    int i = __builtin_bit_cast(int, v);
    i = __builtin_amdgcn_update_dpp(i, i, IMM, 0xF, 0xF, false);
    return __builtin_bit_cast(float, i);
}
__device__ __forceinline__ float qbg(int g, float v) {          // g constant after unroll
    switch (g) {
    case 0:  return qbcast<0x00>(v);
    case 1:  return qbcast<0x55>(v);
    case 2:  return qbcast<0xAA>(v);
    default: return qbcast<0xFF>(v);
    }
}

// 4 lanes per trajectory. lanes {0,1}=f-MLP, {2,3}=g-MLP; 2 neurons/lane (packed f32).
// R10: vmcnt-leak fix. Staging order per chunk is PREP16 (consume z regs fully)
// -> PREF(next chunk, same 4-reg buffer; WAR forces issue-after-read) -> CHAIN16
// (~2400cy) so any conservative vmcnt(0) at the next consumption is already
// satisfied (HBM ~900cy). Prior rounds issued PREF *before* consumption ->
// ~900cy stall per chunk = the measured ~56cy/step exposure floor.
// Plus s-lookahead distribute: s_{i+1} = (w1x2*x_i + cab[i+1]) + w1x2*d + w1x2*dd
// (pre-term off-chain; critical path from d: max(fma,DPP)+fma = 12cy vs 16cy).
__global__ __launch_bounds__(256)
__attribute__((amdgpu_waves_per_eu(1, 1)))
void sde_quad_kernel(
    const float* __restrict__ noise,
    const float* __restrict__ x0,
    const float* __restrict__ Wf1, const float* __restrict__ bf1,
    const float* __restrict__ Wf2, const float* __restrict__ bf2,
    const float* __restrict__ Wg1, const float* __restrict__ bg1,
    const float* __restrict__ Wg2, const float* __restrict__ bg2,
    float* __restrict__ out, int N, int T)
{
    const int tid = blockIdx.x * blockDim.x + threadIdx.x;
    const int n = tid >> 2;        // trajectory
    const int r = tid & 3;         // role within quad
    if (n >= N) return;
    const int steps = T - 1;
    const bool isf = (r < 2);

    const float* W1 = isf ? Wf1 : Wg1;
    const float* B1 = isf ? bf1 : bg1;
    const float* W2 = isf ? Wf2 : Wg2;
    const float* B2 = isf ? bf2 : bg2;
    const int j0 = (r & 1) * 2;

    const v2f w1x2 = { W1[j0] * TSC,     W1[j0 + 1] * TSC };   // W1[0][j]*2log2e
    const v2f w1t2 = { W1[4 + j0] * TSC, W1[5 + j0] * TSC };   // W1[1][j]*2log2e
    const v2f b12  = { B1[j0] * TSC,     B1[j0 + 1] * TSC };
    const float w2a = W2[j0] * LOG2E, w2b = W2[j0 + 1] * LOG2E;
    const float b2h = B2[0] * LOG2E * 0.5f;
    const float w2a2 = -2.0f * w2a, w2b2 = -2.0f * w2b;
    const float Kc   = w2a + w2b + b2h;  // pair-sum(pd) == (h@W2+b2)*log2e

    float x = x0[0];
    float* __restrict__ outp = out;
    if (r == 0) outp[(unsigned)n * (unsigned)T] = x;

    // Single 4-reg distributed noise buffer: lane r owns steps {4r..4r+3} of a chunk.
    float zA[4];
    v2f   cab[CH];
    float c1v[CH], c0v[CH];

    const int nfull = steps / CH;
    const unsigned uN = (unsigned)N;
    const unsigned lanebase = (unsigned)n + (unsigned)(4 * r) * uN;
    unsigned obase = (unsigned)n * (unsigned)T + 1;
    float vstore = x;
    float kfb = 0.0f;              // float(step base of chunk being prepped), exact int

    auto PREF = [&](int cc) {      // issue AFTER current chunk's zA consumption
        if (cc < nfull) {
            const unsigned b = lanebase + (unsigned)(cc * CH) * uN;
            zA[0] = noise[b];
            zA[1] = noise[b + uN];
            zA[2] = noise[b + 2u * uN];
            zA[3] = noise[b + 3u * uN];
        }
    };

    // All x-independent work for 16 steps; fully consumes zA into c1v/c0v.
    auto PREP16 = [&]() {
        float tpv = kfb * 0.05f;   // exact: kfb integer-valued
        #pragma unroll
        for (int i = 0; i < CH; ++i) {
            const float kfi = kfb + (float)(i + 1);
            const float tn  = kfi * 0.05f;            // exact float(k+1)*0.05f grid
            const float dtk = tn - tpv;               // == jnp.diff(ts)[k] bitwise
            const float sdt = __builtin_amdgcn_sqrtf(dtk);
            cab[i] = w1t2 * tpv + b12;                // pk_fma
            const float zi  = qbg(i >> 2, zA[i & 3]); // DPP quad-broadcast (consumes zA)
            const float mm  = isf ? dtk : sdt * zi;
            c1v[i] = LN2  * mm;
            c0v[i] = EPSV * mm;
            tpv = tn;
        }
        kfb += 16.0f;
    };

    // Serial x-chains with s-lookahead distribute.
    auto CHAIN16 = [&]() {
        v2f spre = w1x2 * x + cab[0];
        #pragma unroll
        for (int i = 0; i < CH; ++i) {
            v2f pre_next;
            if (i + 1 < CH) pre_next = w1x2 * x + cab[i + 1];  // x = x_i, off-chain
            const v2f  s   = spre;
            const v2f  ev  = { __builtin_amdgcn_exp2f(s.x), __builtin_amdgcn_exp2f(s.y) };
            const v2f  e1  = ev + 1.0f;                // pk_add
            const float ra = __builtin_amdgcn_rcpf(e1.x);
            const float rb = __builtin_amdgcn_rcpf(e1.y);
            const float pd = fmaf(w2a2, ra, fmaf(w2b2, rb, Kc));
            const float y2 = pd + dpp_xor1(pd);        // pair-sum -> full y2
            const float u  = __builtin_amdgcn_exp2f(y2);
            const float lg = __builtin_amdgcn_logf(1.0f + u);   // log2
            const float d  = fmaf(lg, c1v[i], c0v[i]);          // (softplus+eps)*m
            const float dd = dpp_xor2(d);
            if (i + 1 < CH) {                          // next s via distribute
                const v2f d2  = { d,  d  };
                const v2f dd2 = { dd, dd };
                spre = w1x2 * d2  + pre_next;          // dep on d: 1 fma
                spre = w1x2 * dd2 + spre;              // dep on dd (DPP) in parallel
            }
            x = (x + d) + dd;                          // off critical path
            vstore = ((i & 3) == r) ? x : vstore;
            if ((i & 3) == 3) { outp[obase + (unsigned)r] = vstore; obase += 4u; }
        }
    };

    if (nfull > 0) PREF(0);        // prologue: one-time full-latency wait in first PREP16

    for (int c = 0; c < nfull; ++c) {
        PREP16();                  // consume zA (chunk c)
        PREF(c + 1);               // re-load zA (chunk c+1); 2400cy of CHAIN16 follow
        CHAIN16();
    }

    // scalar tail (never runs for steps % 16 == 0; kept for generality)
    {
        float kf = kfb;
        float tc = kf * 0.05f;
        for (int k = nfull * CH; k < steps; ++k) {
            const float z   = noise[(unsigned)k * uN + (unsigned)n];
            kf += 1.0f;
            const float tn  = kf * 0.05f;
            const float dtk = tn - tc;
            const float sdt = __builtin_amdgcn_sqrtf(dtk);
            const v2f  cabt = w1t2 * tc + b12;
            const float mm  = isf ? dtk : sdt * z;
            const float c1  = LN2  * mm;
            const float c0  = EPSV * mm;
            const v2f  s    = w1x2 * x + cabt;
            const v2f  ev   = { __builtin_amdgcn_exp2f(s.x), __builtin_amdgcn_exp2f(s.y) };
            const v2f  e1   = ev + 1.0f;
            const float ra  = __builtin_amdgcn_rcpf(e1.x);
            const float rb  = __builtin_amdgcn_rcpf(e1.y);
            const float pd  = fmaf(w2a2, ra, fmaf(w2b2, rb, Kc));
            const float y2  = pd + dpp_xor1(pd);
            const float u   = __builtin_amdgcn_exp2f(y2);
            const float lg  = __builtin_amdgcn_logf(1.0f + u);
            const float d   = fmaf(lg, c1, c0);
            x = (x + d) + dpp_xor2(d);
            if (r == 0) outp[(unsigned)n * (unsigned)T + (unsigned)(k + 1)] = x;
            tc = tn;
        }
    }
}

extern "C" void kernel_launch(void* const* d_in, const int* in_sizes, int n_in,
                              void* d_out, int out_size, void* d_ws, size_t ws_size,
                              hipStream_t stream) {
    const float* ts    = (const float*)d_in[0]; (void)ts;
    const float* x0    = (const float*)d_in[1];
    const float* noise = (const float*)d_in[2];
    const float* Wf1   = (const float*)d_in[3];
    const float* bf1   = (const float*)d_in[4];
    const float* Wf2   = (const float*)d_in[5];
    const float* bf2   = (const float*)d_in[6];
    const float* Wg1   = (const float*)d_in[7];
    const float* bg1   = (const float*)d_in[8];
    const float* Wg2   = (const float*)d_in[9];
    const float* bg2   = (const float*)d_in[10];

    const int T = in_sizes[0];
    const int N = (T > 1) ? in_sizes[2] / (T - 1) : 0;
    float* out = (float*)d_out;

    const int threads = N * 4;
    const int block = 256;
    const int grid = (threads + block - 1) / block;
    hipLaunchKernelGGL(sde_quad_kernel, dim3(grid), dim3(block), 0, stream,
                       noise, x0, Wf1, bf1, Wf2, bf2, Wg1, bg1, Wg2, bg2, out, N, T);
}

// Round 11
// 189.089 us; speedup vs baseline: 1.0490x; 1.0490x over previous
//
#include <hip/hip_runtime.h>

#define EPSV  1e-4f
#define LOG2E 1.44269504088896341f
#define LN2   0.69314718055994531f
#define TSC   (2.0f * LOG2E)

typedef float v2f __attribute__((ext_vector_type(2)));

constexpr int CH = 16;

// DPP quad-permute helpers (VALU pipe, register-only)
__device__ __forceinline__ float dpp_xor1(float v) {
    int i = __builtin_bit_cast(int, v);
    i = __builtin_amdgcn_update_dpp(i, i, 0xB1, 0xF, 0xF, false); // quad_perm [1,0,3,2]
    return __builtin_bit_cast(float, i);
}
__device__ __forceinline__ float dpp_xor2(float v) {
    int i = __builtin_bit_cast(int, v);
    i = __builtin_amdgcn_update_dpp(i, i, 0x4E, 0xF, 0xF, false); // quad_perm [2,3,0,1]
    return __builtin_bit_cast(float, i);
}
template<int IMM>
__device__ __forceinline__ float qbcast(float v) {              // broadcast lane Q of quad (IMM = Q*0x55)
    int i = __builtin_bit_cast(int, v);
    i = __builtin_amdgcn_update_dpp(i, i, IMM, 0xF, 0xF, false);
    return __builtin_bit_cast(float, i);
}
__device__ __forceinline__ float qbg(int g, float v) {          // g constant after unroll
    switch (g) {
    case 0:  return qbcast<0x00>(v);
    case 1:  return qbcast<0x55>(v);
    case 2:  return qbcast<0xAA>(v);
    default: return qbcast<0xFF>(v);
    }
}

// Setup: per-step {dt, sqrt(dt)} on the exact float(k)*0.05f grid (16 KB for 2000 steps).
// Same float expressions as the in-kernel path -> bitwise-identical dt/sdt.
__global__ __launch_bounds__(256) void sde_dt_setup(float2* __restrict__ dtt, int steps)
{
    int k = blockIdx.x * blockDim.x + threadIdx.x;
    if (k >= steps) return;
    const float t0 = (float)k * 0.05f;
    const float t1 = (float)(k + 1) * 0.05f;
    const float dt = t1 - t0;
    dtt[k] = make_float2(dt, __builtin_amdgcn_sqrtf(dt));
}

// 4 lanes per trajectory. lanes {0,1}=f-MLP, {2,3}=g-MLP; 2 neurons/lane (packed f32).
// R11 = R7 skeleton EXACTLY (best measured: PREF(next)->PREP16->CHAIN16, prep arrays
// hoisted, waves_per_eu(1,1)) with ONE delta: per-step sqrt + time-diff replaced by a
// {dt,sdt} table riding the proven owner-lane distributed prefetch (lane r owns steps
// 4r..4r+3; z*sdt multiplied at PREP entry, one chunk after load -> no vmcnt stall;
// per-step DPP broadcast same as z). CHAIN16 numerics byte-identical to R7.
template<bool TBL>
__global__ __launch_bounds__(256)
__attribute__((amdgpu_waves_per_eu(1, 1)))
void sde_quad_kernel(
    const float* __restrict__ noise,
    const float* __restrict__ x0,
    const float* __restrict__ Wf1, const float* __restrict__ bf1,
    const float* __restrict__ Wf2, const float* __restrict__ bf2,
    const float* __restrict__ Wg1, const float* __restrict__ bg1,
    const float* __restrict__ Wg2, const float* __restrict__ bg2,
    const float2* __restrict__ dtt,
    float* __restrict__ out, int N, int T)
{
    const int tid = blockIdx.x * blockDim.x + threadIdx.x;
    const int n = tid >> 2;        // trajectory
    const int r = tid & 3;         // role within quad
    if (n >= N) return;
    const int steps = T - 1;
    const bool isf = (r < 2);

    const float* W1 = isf ? Wf1 : Wg1;
    const float* B1 = isf ? bf1 : bg1;
    const float* W2 = isf ? Wf2 : Wg2;
    const float* B2 = isf ? bf2 : bg2;
    const int j0 = (r & 1) * 2;

    const v2f w1x2 = { W1[j0] * TSC,     W1[j0 + 1] * TSC };   // W1[0][j]*2log2e
    const v2f w1t2 = { W1[4 + j0] * TSC, W1[5 + j0] * TSC };   // W1[1][j]*2log2e
    const v2f b12  = { B1[j0] * TSC,     B1[j0 + 1] * TSC };
    const float w2a = W2[j0] * LOG2E, w2b = W2[j0 + 1] * LOG2E;
    const float b2h = B2[0] * LOG2E * 0.5f;
    const float w2a2 = -2.0f * w2a, w2b2 = -2.0f * w2b;
    const float Kc   = w2a + w2b + b2h;  // pair-sum(pd) == (h@W2+b2)*log2e

    float x = x0[0];
    float* __restrict__ outp = out;
    if (r == 0) outp[(unsigned)n * (unsigned)T] = x;

    // Distributed prefetch: lane r owns steps {4r..4r+3} of each 16-chunk.
    float  zA[4], zB[4];
    float2 dA[4], dB[4];
    v2f   cab[CH];
    float c1v[CH], c0v[CH];

    const int nfull = steps / CH;
    const unsigned uN = (unsigned)N;
    const unsigned lanebase = (unsigned)n + (unsigned)(4 * r) * uN;
    unsigned obase = (unsigned)n * (unsigned)T + 1;
    float vstore = x;
    float kfb = 0.0f;              // float(step base of chunk being prepped), exact int

    auto PREF = [&](float (&zb)[4], float2 (&db)[4], int cc) {
        if (cc < nfull) {
            const unsigned b = lanebase + (unsigned)(cc * CH) * uN;
            zb[0] = noise[b];
            zb[1] = noise[b + uN];
            zb[2] = noise[b + 2u * uN];
            zb[3] = noise[b + 3u * uN];
            if constexpr (TBL) {
                const unsigned tb = (unsigned)(cc * CH + 4 * r);
                db[0] = dtt[tb];
                db[1] = dtt[tb + 1];
                db[2] = dtt[tb + 2];
                db[3] = dtt[tb + 3];
            }
        }
    };

    // All x-independent work for 16 steps (fill material for the chains).
    auto PREP16 = [&](const float (&zb)[4], const float2 (&db)[4]) {
        float mz4[4];
        if constexpr (TBL) {
            #pragma unroll
            for (int j = 0; j < 4; ++j) mz4[j] = db[j].y * zb[j];  // sdt*z (owner), data >=1 chunk old
        }
        float tpv = kfb * 0.05f;   // exact: kfb integer-valued
        #pragma unroll
        for (int i = 0; i < CH; ++i) {
            cab[i] = w1t2 * tpv + b12;                // pk_fma (t at step start)
            float mm;
            if constexpr (TBL) {
                const float dtb = qbg(i >> 2, db[i & 3].x);   // DPP broadcast dt
                const float mzb = qbg(i >> 2, mz4[i & 3]);    // DPP broadcast sdt*z
                mm = isf ? dtb : mzb;
                tpv = (kfb + (float)(i + 1)) * 0.05f;         // exact grid t[k+1]
            } else {
                const float kfi = kfb + (float)(i + 1);
                const float tn  = kfi * 0.05f;
                const float dtk = tn - tpv;                   // == jnp.diff(ts)[k] bitwise
                const float sdt = __builtin_amdgcn_sqrtf(dtk);
                const float zi  = qbg(i >> 2, zb[i & 3]);
                mm = isf ? dtk : sdt * zi;
                tpv = tn;
            }
            c1v[i] = LN2  * mm;
            c0v[i] = EPSV * mm;
        }
        kfb += 16.0f;
    };

    // Serial x-chains (R7 numerics exactly: two rcps, no clamp, no lookahead).
    auto CHAIN16 = [&]() {
        #pragma unroll
        for (int i = 0; i < CH; ++i) {
            const v2f  s   = w1x2 * x + cab[i];        // pk_fma, chain head
            const v2f  ev  = { __builtin_amdgcn_exp2f(s.x), __builtin_amdgcn_exp2f(s.y) };
            const v2f  e1  = ev + 1.0f;                // pk_add
            const float ra = __builtin_amdgcn_rcpf(e1.x);
            const float rb = __builtin_amdgcn_rcpf(e1.y);
            const float pd = fmaf(w2a2, ra, fmaf(w2b2, rb, Kc));
            const float y2 = pd + dpp_xor1(pd);        // pair-sum -> full y2
            const float u  = __builtin_amdgcn_exp2f(y2);
            const float lg = __builtin_amdgcn_logf(1.0f + u);   // log2
            const float d  = fmaf(lg, c1v[i], c0v[i]);          // (softplus+eps)*m
            x = (x + d) + dpp_xor2(d);                 // combine f+g across quad
            vstore = ((i & 3) == r) ? x : vstore;
            if ((i & 3) == 3) { outp[obase + (unsigned)r] = vstore; obase += 4u; }
        }
    };

    if (nfull > 0) PREF(zA, dA, 0);

    int c = 0;
    while (c + 2 <= nfull) {
        PREF(zB, dB, c + 1);
        PREP16(zA, dA);
        CHAIN16();
        PREF(zA, dA, c + 2);
        PREP16(zB, dB);
        CHAIN16();
        c += 2;
    }
    if (c < nfull) {       // odd leftover chunk (nfull=125 -> taken; data in zA/dA)
        PREP16(zA, dA);
        CHAIN16();
        ++c;
    }

    // scalar tail (never runs for steps % 16 == 0; kept for generality)
    {
        float kf = kfb;
        float tc = kf * 0.05f;
        for (int k = nfull * CH; k < steps; ++k) {
            const float z   = noise[(unsigned)k * uN + (unsigned)n];
            kf += 1.0f;
            const float tn  = kf * 0.05f;
            const float dtk = tn - tc;
            const float sdt = __builtin_amdgcn_sqrtf(dtk);
            const v2f  cabt = w1t2 * tc + b12;
            const float mm  = isf ? dtk : sdt * z;
            const float c1  = LN2  * mm;
            const float c0  = EPSV * mm;
            const v2f  s    = w1x2 * x + cabt;
            const v2f  ev   = { __builtin_amdgcn_exp2f(s.x), __builtin_amdgcn_exp2f(s.y) };
            const v2f  e1   = ev + 1.0f;
            const float ra  = __builtin_amdgcn_rcpf(e1.x);
            const float rb  = __builtin_amdgcn_rcpf(e1.y);
            const float pd  = fmaf(w2a2, ra, fmaf(w2b2, rb, Kc));
            const float y2  = pd + dpp_xor1(pd);
            const float u   = __builtin_amdgcn_exp2f(y2);
            const float lg  = __builtin_amdgcn_logf(1.0f + u);
            const float d   = fmaf(lg, c1, c0);
            x = (x + d) + dpp_xor2(d);
            if (r == 0) outp[(unsigned)n * (unsigned)T + (unsigned)(k + 1)] = x;
            tc = tn;
        }
    }
}

extern "C" void kernel_launch(void* const* d_in, const int* in_sizes, int n_in,
                              void* d_out, int out_size, void* d_ws, size_t ws_size,
                              hipStream_t stream) {
    const float* ts    = (const float*)d_in[0]; (void)ts;
    const float* x0    = (const float*)d_in[1];
    const float* noise = (const float*)d_in[2];
    const float* Wf1   = (const float*)d_in[3];
    const float* bf1   = (const float*)d_in[4];
    const float* Wf2   = (const float*)d_in[5];
    const float* bf2   = (const float*)d_in[6];
    const float* Wg1   = (const float*)d_in[7];
    const float* bg1   = (const float*)d_in[8];
    const float* Wg2   = (const float*)d_in[9];
    const float* bg2   = (const float*)d_in[10];

    const int T = in_sizes[0];
    const int N = (T > 1) ? in_sizes[2] / (T - 1) : 0;
    const int steps = T - 1;
    float* out = (float*)d_out;

    const int threads = N * 4;
    const int block = 256;
    const int grid = (threads + block - 1) / block;

    const bool use_tbl = (steps > 0) && (d_ws != nullptr) &&
                         (ws_size >= (size_t)steps * sizeof(float2));

    if (use_tbl) {
        const int sgrid = (steps + block - 1) / block;
        hipLaunchKernelGGL(sde_dt_setup, dim3(sgrid), dim3(block), 0, stream,
                           (float2*)d_ws, steps);
        hipLaunchKernelGGL((sde_quad_kernel<true>), dim3(grid), dim3(block), 0, stream,
                           noise, x0, Wf1, bf1, Wf2, bf2, Wg1, bg1, Wg2, bg2,
                           (const float2*)d_ws, out, N, T);
    } else {
        hipLaunchKernelGGL((sde_quad_kernel<false>), dim3(grid), dim3(block), 0, stream,
                           noise, x0, Wf1, bf1, Wf2, bf2, Wg1, bg1, Wg2, bg2,
                           (const float2*)nullptr, out, N, T);
    }
}

// Round 12
// 173.362 us; speedup vs baseline: 1.1442x; 1.0907x over previous
//
#include <hip/hip_runtime.h>

#define EPSV  1e-4f
#define LOG2E 1.44269504088896341f
#define LN2   0.69314718055994531f
#define TSC   (2.0f * LOG2E)

typedef float v2f __attribute__((ext_vector_type(2)));

constexpr int CH = 16;

// DPP quad-permute helpers (VALU pipe, register-only)
__device__ __forceinline__ float dpp_xor1(float v) {
    int i = __builtin_bit_cast(int, v);
    i = __builtin_amdgcn_update_dpp(i, i, 0xB1, 0xF, 0xF, false); // quad_perm [1,0,3,2]
    return __builtin_bit_cast(float, i);
}
__device__ __forceinline__ float dpp_xor2(float v) {
    int i = __builtin_bit_cast(int, v);
    i = __builtin_amdgcn_update_dpp(i, i, 0x4E, 0xF, 0xF, false); // quad_perm [2,3,0,1]
    return __builtin_bit_cast(float, i);
}
template<int IMM>
__device__ __forceinline__ float qbcast(float v) {              // broadcast lane Q of quad (IMM = Q*0x55)
    int i = __builtin_bit_cast(int, v);
    i = __builtin_amdgcn_update_dpp(i, i, IMM, 0xF, 0xF, false);
    return __builtin_bit_cast(float, i);
}
__device__ __forceinline__ float qbg(int g, float v) {          // g constant after unroll
    switch (g) {
    case 0:  return qbcast<0x00>(v);
    case 1:  return qbcast<0x55>(v);
    case 2:  return qbcast<0xAA>(v);
    default: return qbcast<0xFF>(v);
    }
}

// 4 lanes per trajectory. lanes {0,1}=f-MLP, {2,3}=g-MLP; 2 neurons/lane (packed f32).
// FINAL = R7 structure (best measured across 12 rounds: 165.8 µs bench).
// Wall is pinned by the serial dependency chain (~200cy: 4 dependent transcendentals
// + DPP/VALU links) at 1 wave/SIMD (grid-pinned). Verified dead ends: per-step memory
// paths of any kind (VMEM/LDS tables: R2/R4/R8/R9/R11 all regress), 2 waves/SIMD
// (R3: per-wave overhead doubles), chain-ILP restructures (R9/R10), occupancy attrs
// alone (R6). Keep: register-only prep, hoisted into arrays (R7), distributed noise
// prefetch + DPP broadcast (R5), waves_per_eu(1,1) + prep-hoist (R7, VGPR 32->132).
__global__ __launch_bounds__(256)
__attribute__((amdgpu_waves_per_eu(1, 1)))
void sde_quad_kernel(
    const float* __restrict__ noise,
    const float* __restrict__ x0,
    const float* __restrict__ Wf1, const float* __restrict__ bf1,
    const float* __restrict__ Wf2, const float* __restrict__ bf2,
    const float* __restrict__ Wg1, const float* __restrict__ bg1,
    const float* __restrict__ Wg2, const float* __restrict__ bg2,
    float* __restrict__ out, int N, int T)
{
    const int tid = blockIdx.x * blockDim.x + threadIdx.x;
    const int n = tid >> 2;        // trajectory
    const int r = tid & 3;         // role within quad
    if (n >= N) return;
    const int steps = T - 1;
    const bool isf = (r < 2);

    const float* W1 = isf ? Wf1 : Wg1;
    const float* B1 = isf ? bf1 : bg1;
    const float* W2 = isf ? Wf2 : Wg2;
    const float* B2 = isf ? bf2 : bg2;
    const int j0 = (r & 1) * 2;

    const v2f w1x2 = { W1[j0] * TSC,     W1[j0 + 1] * TSC };   // W1[0][j]*2log2e
    const v2f w1t2 = { W1[4 + j0] * TSC, W1[5 + j0] * TSC };   // W1[1][j]*2log2e
    const v2f b12  = { B1[j0] * TSC,     B1[j0 + 1] * TSC };
    const float w2a = W2[j0] * LOG2E, w2b = W2[j0 + 1] * LOG2E;
    const float b2h = B2[0] * LOG2E * 0.5f;
    const float w2a2 = -2.0f * w2a, w2b2 = -2.0f * w2b;
    const float Kc   = w2a + w2b + b2h;  // pair-sum(pd) == (h@W2+b2)*log2e

    float x = x0[0];
    float* __restrict__ outp = out;
    if (r == 0) outp[(unsigned)n * (unsigned)T] = x;

    // Distributed noise prefetch: lane r owns steps {4r..4r+3} of each 16-chunk.
    float zA[4], zB[4];
    // Per-chunk prep register arrays (constant-indexed after full unroll -> VGPRs).
    v2f   cab[CH];
    float c1v[CH], c0v[CH];

    const int nfull = steps / CH;
    const unsigned uN = (unsigned)N;
    const unsigned lanebase = (unsigned)n + (unsigned)(4 * r) * uN;
    unsigned obase = (unsigned)n * (unsigned)T + 1;
    float vstore = x;
    float kfb = 0.0f;      // float(step index at chunk base), exact integer in f32
    float tcarry = 0.0f;   // t at chunk base = kfb*0.05f (carried exactly)

    auto PREF = [&](float (&zb)[4], int cc) {
        if (cc < nfull) {
            const unsigned b = lanebase + (unsigned)(cc * CH) * uN;
            zb[0] = noise[b];
            zb[1] = noise[b + uN];
            zb[2] = noise[b + 2u * uN];
            zb[3] = noise[b + 3u * uN];
        }
    };

    // All x-independent work for 16 steps (fill material for the chains).
    auto PREP16 = [&](const float (&zb)[4]) {
        float tpv = tcarry;
        #pragma unroll
        for (int i = 0; i < CH; ++i) {
            const float kfi = kfb + (float)(i + 1);
            const float tn  = kfi * 0.05f;            // exact float(k+1)*0.05f grid
            const float dtk = tn - tpv;               // == jnp.diff(ts)[k] bitwise
            const float sdt = __builtin_amdgcn_sqrtf(dtk);
            cab[i] = w1t2 * tpv + b12;                // pk_fma (t at step start)
            const float z   = qbg(i >> 2, zb[i & 3]); // DPP quad-broadcast
            const float mz  = sdt * z;
            const float mm  = isf ? dtk : mz;         // f: dt ; g: sqrt(dt)*z
            c1v[i] = LN2  * mm;
            c0v[i] = EPSV * mm;
            tpv = tn;
        }
        tcarry = tpv;
        kfb += 16.0f;
    };

    // The serial x-chains (prep already in registers).
    auto CHAIN16 = [&]() {
        #pragma unroll
        for (int i = 0; i < CH; ++i) {
            const v2f  s   = w1x2 * x + cab[i];       // pk_fma, chain head
            const v2f  ev  = { __builtin_amdgcn_exp2f(s.x), __builtin_amdgcn_exp2f(s.y) };
            const v2f  e1  = ev + 1.0f;               // pk_add
            const float ra = __builtin_amdgcn_rcpf(e1.x);
            const float rb = __builtin_amdgcn_rcpf(e1.y);
            const float pd = fmaf(w2a2, ra, fmaf(w2b2, rb, Kc));
            const float y2 = pd + dpp_xor1(pd);       // pair-sum -> full y2
            const float u  = __builtin_amdgcn_exp2f(y2);
            const float lg = __builtin_amdgcn_logf(1.0f + u);   // log2
            const float d  = fmaf(lg, c1v[i], c0v[i]);          // (softplus+eps)*m
            x = (x + d) + dpp_xor2(d);                // combine f+g across quad
            vstore = ((i & 3) == r) ? x : vstore;
            if ((i & 3) == 3) { outp[obase + (unsigned)r] = vstore; obase += 4u; }
        }
    };

    if (nfull > 0) PREF(zA, 0);

    int c = 0;
    while (c + 2 <= nfull) {
        PREF(zB, c + 1);
        PREP16(zA);
        CHAIN16();
        PREF(zA, c + 2);
        PREP16(zB);
        CHAIN16();
        c += 2;
    }
    if (c < nfull) {       // odd leftover chunk (nfull=125 -> taken; data in zA)
        PREP16(zA);
        CHAIN16();
        ++c;
    }

    // scalar tail (never runs for steps % 16 == 0; kept for generality)
    {
        float kf = kfb, tc = tcarry;
        for (int k = nfull * CH; k < steps; ++k) {
            const float z   = noise[(unsigned)k * uN + (unsigned)n];
            kf += 1.0f;
            const float tn  = kf * 0.05f;
            const float dtk = tn - tc;
            const float sdt = __builtin_amdgcn_sqrtf(dtk);
            const v2f  cabt = w1t2 * tc + b12;
            const float mm  = isf ? dtk : sdt * z;
            const float c1  = LN2  * mm;
            const float c0  = EPSV * mm;
            const v2f  s    = w1x2 * x + cabt;
            const v2f  ev   = { __builtin_amdgcn_exp2f(s.x), __builtin_amdgcn_exp2f(s.y) };
            const v2f  e1   = ev + 1.0f;
            const float ra  = __builtin_amdgcn_rcpf(e1.x);
            const float rb  = __builtin_amdgcn_rcpf(e1.y);
            const float pd  = fmaf(w2a2, ra, fmaf(w2b2, rb, Kc));
            const float y2  = pd + dpp_xor1(pd);
            const float u   = __builtin_amdgcn_exp2f(y2);
            const float lg  = __builtin_amdgcn_logf(1.0f + u);
            const float d   = fmaf(lg, c1, c0);
            x = (x + d) + dpp_xor2(d);
            if (r == 0) outp[(unsigned)n * (unsigned)T + (unsigned)(k + 1)] = x;
            tc = tn;
        }
    }
}

extern "C" void kernel_launch(void* const* d_in, const int* in_sizes, int n_in,
                              void* d_out, int out_size, void* d_ws, size_t ws_size,
                              hipStream_t stream) {
    const float* ts    = (const float*)d_in[0]; (void)ts;
    const float* x0    = (const float*)d_in[1];
    const float* noise = (const float*)d_in[2];
    const float* Wf1   = (const float*)d_in[3];
    const float* bf1   = (const float*)d_in[4];
    const float* Wf2   = (const float*)d_in[5];
    const float* bf2   = (const float*)d_in[6];
    const float* Wg1   = (const float*)d_in[7];
    const float* bg1   = (const float*)d_in[8];
    const float* Wg2   = (const float*)d_in[9];
    const float* bg2   = (const float*)d_in[10];

    const int T = in_sizes[0];
    const int N = (T > 1) ? in_sizes[2] / (T - 1) : 0;
    float* out = (float*)d_out;

    const int threads = N * 4;
    const int block = 256;
    const int grid = (threads + block - 1) / block;
    hipLaunchKernelGGL(sde_quad_kernel, dim3(grid), dim3(block), 0, stream,
                       noise, x0, Wf1, bf1, Wf2, bf2, Wg1, bg1, Wg2, bg2, out, N, T);
}